// Round 11
// baseline (223.803 us; speedup 1.0000x reference)
//
#include <hip/hip_runtime.h>
#include <math.h>

// MinGRU: B=8, S=8192, D=256, H=256, fp32 in/out.  TWO-PASS RECOMPUTE:
//   K0 prep_w   : weights-only fp32->bf16 (256 KiB, ~3 us).
//   K1 gemm_sum : bf16-MFMA dual GEMM (512 thr / 128x128 tile); stores
//                 ONLY per-chunk (P,Q) summaries (2 MB).
//   K2 phaseB   : sequential scan over 128 chunk summaries (batch-32).
//   K3 gemm_out : recomputes the GEMM bit-identically; in-register prefix
//                 epilogue (ordered shfl inclusive prefix over q +
//                 lane-local chain over i) writes out directly.
// R11: T14 async-stage split in the GEMM body -- next k0's x tile is
//   loaded into regs right after the current LDS write, so its HBM/LLC
//   latency hides under barrier+ds_read+MFMA instead of serializing
//   (R10: MfmaUtil 14%, stage latency exposed 4x per block).
//   x-only prefetch (+16 VGPR, peak ~127 of the 128 cap at (512,4)).
// R10 lessons: ab cannot be LDS-resident chip-wide (64MB > 40MB total);
//   two-pass != ab round-trip in cost -- both ~100us of GPU parts.
// R8 lesson: occupancy alone is a weak lever (18->29% gave ~0).
// R1/R2 lesson: register-resident scan across a grid sync always spills.

constexpr int B_ = 8;
constexpr int S_ = 8192;
constexpr int D_ = 256;
constexpr int H_ = 256;
constexpr int M_ = B_ * S_;        // 65536 rows
constexpr int CHUNKS = 128;
constexpr int CLEN = S_ / CHUNKS;  // 64

typedef __attribute__((ext_vector_type(8))) short bf16x8;
typedef __attribute__((ext_vector_type(4))) float f32x4;

// 2 floats -> 2 bf16 (round-to-nearest, ties-away): 2 adds + 1 v_perm.
__device__ __forceinline__ uint pack2bf(float f0, float f1) {
  const uint u0 = __float_as_uint(f0) + 0x8000u;
  const uint u1 = __float_as_uint(f1) + 0x8000u;
  return __builtin_amdgcn_perm(u1, u0, 0x07060302u);
}

__device__ __forceinline__ float a_of(uint u) { return __uint_as_float(u << 16); }
__device__ __forceinline__ float b_of(uint u) { return __uint_as_float(u & 0xFFFF0000u); }

// ---------------------------------------------------------------- prep ----
__global__ __launch_bounds__(256) void prep_w(
    const float* __restrict__ wzw, const float* __restrict__ whw,
    uint4* __restrict__ wb)
{
  const int u = blockIdx.x * 256 + threadIdx.x;   // 0..16383 (8192 per proj)
  const int proj = u >> 13;
  const float* s = (proj ? whw : wzw) + (size_t)(u & 8191) * 8;
  wb[u] = make_uint4(pack2bf(s[0], s[1]), pack2bf(s[2], s[3]),
                     pack2bf(s[4], s[5]), pack2bf(s[6], s[7]));
}

// ------------------------------------------------------- shared GEMM body --
// Block: 512 thr = 8 waves. Tile: 128 rows x 128 ch, both projections.
// LDS rows padded to 72 bf16 (144B: uint4-aligned, conflict-free b128).
// Wave w: rows mb..mb+63 (one 64-step chunk), channels nb..nb+31.
// T14: x tile for k0+1 prefetched into xv[] during k0's write phase;
// x-stage indexing: row = (tid>>4) + 32f, seg = tid&15 (f-invariant).
#define GEMM_PREAMBLE(xptr, wptr)                                            \
  __shared__ ushort xs[128][72];                                             \
  __shared__ ushort wzs[128][72];                                            \
  __shared__ ushort whs[128][72];                                            \
  const int tid = threadIdx.x;                                               \
  const int g    = blockIdx.x;                                               \
  const int xcd  = g & 7;                                                    \
  const int loc  = g >> 3;                                                   \
  const int nt   = loc & 1;                                                  \
  const int panel = (loc >> 1) * 8 + xcd;                                    \
  const int m0 = panel * 128;                                                \
  const int n0 = nt * 128;                                                   \
  const int lane = tid & 63;                                                 \
  const int w  = tid >> 6;                                                   \
  const int mb = (w & 1) * 64;                                               \
  const int nb = (w >> 1) * 32;                                              \
  const int q  = lane >> 4;                                                  \
  const int cn = lane & 15;                                                  \
  const int segx = tid & 15;                                                 \
  const int rxb  = tid >> 4;                                                 \
  f32x4 accz[4][2] = {};                                                     \
  f32x4 acch[4][2] = {};                                                     \
  float4 xv[4];                                                              \
  _Pragma("unroll")                                                          \
  for (int f = 0; f < 4; f++)                                                \
    xv[f] = *(const float4*)(xptr + (size_t)(m0 + rxb + 32 * f) * D_ +       \
                             segx * 4);                                      \
  for (int k0 = 0; k0 < D_; k0 += 64) {                                      \
    __syncthreads();                                                         \
    _Pragma("unroll")                                                        \
    for (int f = 0; f < 4; f++)                                              \
      *(uint2*)&xs[rxb + 32 * f][segx * 4] =                                 \
          make_uint2(pack2bf(xv[f].x, xv[f].y), pack2bf(xv[f].z, xv[f].w));  \
    _Pragma("unroll")                                                        \
    for (int f = 0; f < 4; f++) {                                            \
      const int idx = tid + 512 * f;                                         \
      const int proj = idx >> 10;                                            \
      const int r   = (idx >> 3) & 127, seg = idx & 7;                       \
      const uint4 v = *(const uint4*)(wptr + (size_t)proj * H_ * D_ +        \
                                      (size_t)(n0 + r) * D_ + k0 + seg * 8); \
      ushort* dst = proj ? &whs[r][seg * 8] : &wzs[r][seg * 8];              \
      *(uint4*)dst = v;                                                      \
    }                                                                        \
    if (k0 + 64 < D_) {  /* T14: issue next x loads before compute */        \
      _Pragma("unroll")                                                      \
      for (int f = 0; f < 4; f++)                                            \
        xv[f] = *(const float4*)(xptr + (size_t)(m0 + rxb + 32 * f) * D_ +   \
                                 (k0 + 64) + segx * 4);                      \
    }                                                                        \
    __syncthreads();                                                         \
    _Pragma("unroll")                                                        \
    for (int ks = 0; ks < 2; ks++) {                                         \
      const int kk = ks * 32 + q * 8;                                        \
      bf16x8 af[4], bz[2], bh[2];                                            \
      _Pragma("unroll")                                                      \
      for (int i = 0; i < 4; i++)                                            \
        af[i] = *(const bf16x8*)&xs[mb + i * 16 + cn][kk];                   \
      _Pragma("unroll")                                                      \
      for (int j = 0; j < 2; j++) {                                          \
        bz[j] = *(const bf16x8*)&wzs[nb + j * 16 + cn][kk];                  \
        bh[j] = *(const bf16x8*)&whs[nb + j * 16 + cn][kk];                  \
      }                                                                      \
      _Pragma("unroll")                                                      \
      for (int i = 0; i < 4; i++)                                            \
        _Pragma("unroll")                                                    \
        for (int j = 0; j < 2; j++) {                                        \
          accz[i][j] = __builtin_amdgcn_mfma_f32_16x16x32_bf16(af[i], bz[j], accz[i][j], 0, 0, 0); \
          acch[i][j] = __builtin_amdgcn_mfma_f32_16x16x32_bf16(af[i], bh[j], acch[i][j], 0, 0, 0); \
        }                                                                    \
    }                                                                        \
  }                                                                          \
  const int row0 = m0 + mb;                                                  \
  const int bb2  = row0 >> 13;                                               \
  const int cc   = (row0 & 8191) >> 6;

// --------------------------------------------------------------- pass 1 ---
// Chunk summaries only. t within chunk = i*16 + q*4 + r.
__global__ __launch_bounds__(512, 4) void gemm_sum(
    const float* __restrict__ x, const ushort* __restrict__ wbu,
    const float* __restrict__ whb, const float* __restrict__ wzb,
    float2* __restrict__ chunkPQ)
{
  GEMM_PREAMBLE(x, wbu)

#pragma unroll
  for (int j = 0; j < 2; j++) {
    const int ch = n0 + nb + j * 16 + cn;
    const float zb = wzb[ch], hb = whb[ch];
    float P[4], Q[4];
#pragma unroll
    for (int i = 0; i < 4; i++) {
      float Pi = 1.f, Qi = 0.f;
#pragma unroll
      for (int r = 0; r < 4; r++) {
        const float zpre = accz[i][j][r] + zb;
        const float hpre = acch[i][j][r] + hb;
        const float e = __expf(-zpre);
        const float rcp = __builtin_amdgcn_rcpf(1.0f + e);  // z
        const uint pk = pack2bf(e * rcp, hpre * rcp);  // keep rounding parity
        Qi = fmaf(a_of(pk), Qi, b_of(pk));
        Pi *= a_of(pk);
      }
      P[i] = Pi; Q[i] = Qi;
    }
    // all-reduce over q (t-order aware butterfly), then fold i.
#pragma unroll
    for (int i = 0; i < 4; i++) {
      {
        const float Pp = __shfl_xor(P[i], 16);
        const float Qp = __shfl_xor(Q[i], 16);
        const bool later = (lane & 16) != 0;
        Q[i] = later ? fmaf(P[i], Qp, Q[i]) : fmaf(Pp, Q[i], Qp);
        P[i] = P[i] * Pp;
      }
      {
        const float Pp = __shfl_xor(P[i], 32);
        const float Qp = __shfl_xor(Q[i], 32);
        const bool later = (lane & 32) != 0;
        Q[i] = later ? fmaf(P[i], Qp, Q[i]) : fmaf(Pp, Q[i], Qp);
        P[i] = P[i] * Pp;
      }
    }
    float Pc = P[0], Qc = Q[0];
#pragma unroll
    for (int i = 1; i < 4; i++) {
      Qc = fmaf(P[i], Qc, Q[i]);
      Pc *= P[i];
    }
    if (lane < 16)
      chunkPQ[((size_t)bb2 * CHUNKS + cc) * H_ + ch] = make_float2(Pc, Qc);
  }
}

// --------------------------------------------------------------- phase B --
// 8 blocks x 256 thr; batch-32 prefetch (4 latency exposures, was 8).
__global__ __launch_bounds__(256) void scan_phaseB(
    const float* __restrict__ h0in, const float2* __restrict__ pq,
    float* __restrict__ hstate)
{
  const int b = blockIdx.x;
  const int h = threadIdx.x;
  const size_t base = (size_t)b * CHUNKS * H_ + h;
  float hc = h0in[(size_t)b * H_ + h];
  for (int c0 = 0; c0 < CHUNKS; c0 += 32) {
    float2 v[32];
#pragma unroll
    for (int j = 0; j < 32; j++)
      v[j] = pq[base + (size_t)(c0 + j) * H_];
#pragma unroll
    for (int j = 0; j < 32; j++) {
      hstate[base + (size_t)(c0 + j) * H_] = hc;
      hc = fmaf(v[j].x, hc, v[j].y);
    }
  }
}

// --------------------------------------------------------------- pass 2 ---
// Recompute a,b; prefix-scan h in registers; write out directly.
__global__ __launch_bounds__(512, 4) void gemm_out(
    const float* __restrict__ x, const ushort* __restrict__ wbu,
    const float* __restrict__ whb, const float* __restrict__ wzb,
    const float* __restrict__ hstate, float* __restrict__ out)
{
  GEMM_PREAMBLE(x, wbu)

#pragma unroll
  for (int j = 0; j < 2; j++) {
    const int ch = n0 + nb + j * 16 + cn;
    const float zb = wzb[ch], hb = whb[ch];
    uint u[4][4];
    float P[4], Q[4];
#pragma unroll
    for (int i = 0; i < 4; i++) {
      float Pi = 1.f, Qi = 0.f;
#pragma unroll
      for (int r = 0; r < 4; r++) {
        const float zpre = accz[i][j][r] + zb;
        const float hpre = acch[i][j][r] + hb;
        const float e = __expf(-zpre);
        const float rcp = __builtin_amdgcn_rcpf(1.0f + e);  // z
        const uint pk = pack2bf(e * rcp, hpre * rcp);
        u[i][r] = pk;
        Qi = fmaf(a_of(pk), Qi, b_of(pk));
        Pi *= a_of(pk);
      }
      P[i] = Pi; Q[i] = Qi;
    }
    // Ordered INCLUSIVE prefix over q (lanes q*16+cn; earlier q = earlier t).
#pragma unroll
    for (int i = 0; i < 4; i++) {
#pragma unroll
      for (int d = 1; d <= 2; d++) {
        const int src = (q >= d) ? (lane - 16 * d) : lane;
        const float Pp = __shfl(P[i], src);
        const float Qp = __shfl(Q[i], src);
        if (q >= d) {
          Q[i] = fmaf(P[i], Qp, Q[i]);
          P[i] = P[i] * Pp;
        }
      }
    }
    // h at chunk start for this channel.
    float hst = hstate[((size_t)bb2 * CHUNKS + cc) * H_ + ch];
#pragma unroll
    for (int i = 0; i < 4; i++) {
      // subchunk-i total: q=3's inclusive value (lane cn+48).
      const float Tp = __shfl(P[i], cn + 48);
      const float Tq = __shfl(Q[i], cn + 48);
      // exclusive prefix for this lane: q-1's inclusive, identity at q=0.
      const float Ps = __shfl(P[i], (q > 0) ? (lane - 16) : lane);
      const float Qs = __shfl(Q[i], (q > 0) ? (lane - 16) : lane);
      const float Pe = (q == 0) ? 1.f : Ps;
      const float Qe = (q == 0) ? 0.f : Qs;
      // h at t = i*16 + q*4, then 4-step replay with direct store.
      float hcur = fmaf(Pe, hst, Qe);
#pragma unroll
      for (int r = 0; r < 4; r++) {
        hcur = fmaf(a_of(u[i][r]), hcur, b_of(u[i][r]));
        out[(size_t)(m0 + mb + i * 16 + q * 4 + r) * H_ + ch] = hcur;
      }
      // advance chunk-start h past subchunk i (all lanes, uniform per cn).
      hst = fmaf(Tp, hst, Tq);
    }
  }
}

extern "C" void kernel_launch(void* const* d_in, const int* in_sizes, int n_in,
                              void* d_out, int out_size, void* d_ws, size_t ws_size,
                              hipStream_t stream) {
  const float* x   = (const float*)d_in[0];
  const float* h0  = (const float*)d_in[1];
  const float* whw = (const float*)d_in[2];
  const float* whb = (const float*)d_in[3];
  const float* wzw = (const float*)d_in[4];
  const float* wzb = (const float*)d_in[5];
  float* out = (float*)d_out;

  float2* chunkPQ = (float2*)d_ws;                        // [B,CHUNKS,H]
  float*  hstate  = (float*)(chunkPQ + (size_t)B_ * CHUNKS * H_);  // [B,CHUNKS,H]
  ushort* wb      = (ushort*)(hstate + (size_t)B_ * CHUNKS * H_);  // [2,H,D] bf16

  prep_w<<<64, 256, 0, stream>>>(wzw, whw, (uint4*)wb);
  gemm_sum<<<(M_ / 128) * (H_ / 128), 512, 0, stream>>>(
      x, wb, whb, wzb, chunkPQ);
  scan_phaseB<<<B_, 256, 0, stream>>>(h0, (const float2*)chunkPQ, hstate);
  gemm_out<<<(M_ / 128) * (H_ / 128), 512, 0, stream>>>(
      x, wb, whb, wzb, hstate, out);
}